// Round 2
// baseline (139.766 us; speedup 1.0000x reference)
//
#include <hip/hip_runtime.h>

// Problem constants (fixed by the reference).
#define BATCH 16384
#define DIN   128
#define HIDN  16
#define NNODE 255
#define NLEAF 256

typedef _Float16 half8 __attribute__((ext_vector_type(8)));
typedef _Float16 half4 __attribute__((ext_vector_type(4)));
typedef float   float4v __attribute__((ext_vector_type(4)));

// ---------------- combined pack kernel ----------------
// blocks 0..1023: pack x -> f16 B-operand fragments
//   lane L holds B[k=(L>>4)*8+j][n=L&15] (n=batch, k=din); ws: [bt][kc][lane] half8
// blocks 1024..1278: pack W1[n] -> f16 A-operand fragments (LDS-staged)
//   lane L holds A[m=L&15][k=(L>>4)*8+j] (m=hidden, k=din); plus W2[n] -> f16
__global__ __launch_bounds__(256) void k_pack(const float* __restrict__ x, const float* __restrict__ w1,
                                              const float* __restrict__ w2,
                                              half8* __restrict__ xp, half8* __restrict__ w1p,
                                              _Float16* __restrict__ w2h) {
    __shared__ float w[DIN * 17];
    int t = threadIdx.x;
    if (blockIdx.x < 1024) {
        int gid  = blockIdx.x * 256 + t;
        int lane = gid & 63;
        int kc   = (gid >> 6) & 3;
        int bt   = gid >> 8;
        const float4* src = (const float4*)(x + (size_t)(bt * 16 + (lane & 15)) * DIN + kc * 32 + ((lane >> 4) * 8));
        float4 v0 = src[0], v1 = src[1];
        half8 v;
        v[0] = (_Float16)v0.x; v[1] = (_Float16)v0.y; v[2] = (_Float16)v0.z; v[3] = (_Float16)v0.w;
        v[4] = (_Float16)v1.x; v[5] = (_Float16)v1.y; v[6] = (_Float16)v1.z; v[7] = (_Float16)v1.w;
        xp[gid] = v;
    } else {
        int n = blockIdx.x - 1024;
        const float4* src = (const float4*)(w1 + (size_t)n * (DIN * HIDN)) + t * 2;
        float4 a0 = src[0], a1 = src[1];
        int base = t * 8;
#pragma unroll
        for (int e = 0; e < 4; ++e) {
            int idx0 = base + e, idx1 = base + 4 + e;
            w[(idx0 >> 4) * 17 + (idx0 & 15)] = (&a0.x)[e];
            w[(idx1 >> 4) * 17 + (idx1 & 15)] = (&a1.x)[e];
        }
        __syncthreads();
        int L  = t & 63;
        int kc = t >> 6;
        int m  = L & 15;
        int k0 = kc * 32 + (L >> 4) * 8;
        half8 v;
#pragma unroll
        for (int j = 0; j < 8; ++j) v[j] = (_Float16)w[(k0 + j) * 17 + m];
        w1p[(size_t)n * 256 + t] = v;
        if (t < HIDN) w2h[n * HIDN + t] = (_Float16)w2[n * HIDN + t];
    }
}

// ---------------- fused MLP + tree kernel ----------------
// Grid 256 blocks (1/CU), 256 threads (4 waves), 64 batch rows per block.
// Phase 1 (MLP): waves split the 255 nodes round-robin (n == wv mod 4); each wave
//   computes ALL 4 row-tiles (64 rows) for its nodes via double MFMA, writing
//   sigmoid(logit) into LDS sp[64][260]. Node-fragment reads hit L2 (w1p is 1 MB,
//   XCD-resident); each fragment is read by exactly ONE wave (no redundancy).
//   4 independent tile-chains per node give the MFMA pipe ILP at 1 wave/SIMD;
//   depth-1 operand prefetch hides L2 latency.
// Phase 2 (tree): one barrier, then each wave scans 16 rows straight out of LDS.
// The 16.7 MB p_ws intermediate and the third kernel launch are gone.
__global__ __launch_bounds__(256, 1) void k_fused(const half8* __restrict__ xp, const half8* __restrict__ w1p,
                                                  const float* __restrict__ b1, const _Float16* __restrict__ w2h,
                                                  const float* __restrict__ b2, const float* __restrict__ leaf,
                                                  float* __restrict__ h_out, float* __restrict__ pp_out,
                                                  float* __restrict__ p_out, float* __restrict__ nr_out) {
    __shared__ float sp[64][260];                 // stride 260 words -> 2-way banks (free)
    int wv   = threadIdx.x >> 6;
    int lane = threadIdx.x & 63;
    int q    = lane >> 4;
    int bt0  = blockIdx.x * 4;                    // four 16-row tiles

    // B-fragments for all 4 tiles (identical in every wave)
    half8 bq[4][4];
#pragma unroll
    for (int t = 0; t < 4; ++t)
#pragma unroll
        for (int kc = 0; kc < 4; ++kc)
            bq[t][kc] = xp[(size_t)((bt0 + t) * 4 + kc) * 64 + lane];
    asm volatile("" ::: "memory");

    // ---- phase 1: MLP over this wave's nodes ----
    int cnt = (wv < 3) ? 64 : 63;                 // 255 = 64+64+64+63
    int n   = wv;
    half8 a[4];
#pragma unroll
    for (int kc = 0; kc < 4; ++kc) a[kc] = w1p[(size_t)(n * 4 + kc) * 64 + lane];
    float4 b1f = ((const float4*)(b1 + n * HIDN))[q];
    half4  a2  = *(const half4*)(w2h + n * HIDN + q * 4);
    float  b2v = b2[n];

    for (int i = 0; i < cnt; ++i) {
        int nn = n + ((i + 1 < cnt) ? 4 : 0);     // branch-free clamp
        half8 an[4];
#pragma unroll
        for (int kc = 0; kc < 4; ++kc) an[kc] = w1p[(size_t)(nn * 4 + kc) * 64 + lane];
        float4 b1n = ((const float4*)(b1 + nn * HIDN))[q];
        half4  a2n = *(const half4*)(w2h + nn * HIDN + q * 4);
        float  b2n = b2[nn];

#pragma unroll
        for (int t = 0; t < 4; ++t) {
            float4v acc = {b1f.x, b1f.y, b1f.z, b1f.w};
#pragma unroll
            for (int kc = 0; kc < 4; ++kc)
                acc = __builtin_amdgcn_mfma_f32_16x16x32_f16(a[kc], bq[t][kc], acc, 0, 0, 0);
            half4 rb;
#pragma unroll
            for (int r = 0; r < 4; ++r) rb[r] = (_Float16)fmaxf(acc[r], 0.f);
            float4v acc2 = {b2v, b2v, b2v, b2v};
            acc2 = __builtin_amdgcn_mfma_f32_16x16x16f16(a2, rb, acc2, 0, 0, 0);
            if (lane < 16)
                sp[t * 16 + lane][n] =
                    __builtin_amdgcn_rcpf(1.f + __builtin_amdgcn_exp2f(-1.44269504088896f * acc2[0]));
        }
#pragma unroll
        for (int kc = 0; kc < 4; ++kc) a[kc] = an[kc];
        b1f = b1n; a2 = a2n; b2v = b2n;
        n = nn;
    }
    __syncthreads();

    // ---- phase 2: tree scan, 16 rows per wave, straight from LDS ----
    const float4 lf = *(const float4*)(leaf + 4 * lane);
    for (int rr = 0; rr < 16; ++rr) {
        int r = wv * 16 + rr;
        int b = blockIdx.x * 64 + r;
        const float* P = &sp[r][0];
        float* nr = nr_out + (size_t)b * NNODE;

        // p_out copy (write-once -> nontemporal)
#pragma unroll
        for (int c = 0; c < 4; ++c) {
            int idx = c * 64 + lane;
            if (idx < NNODE)
                __builtin_nontemporal_store(P[idx], &p_out[(size_t)b * NNODE + idx]);
        }

        float pref = 1.f;
#pragma unroll
        for (int l = 0; l < 6; ++l) {
            if ((lane & ((1 << (6 - l)) - 1)) == 0)
                __builtin_nontemporal_store(pref, &nr[(1 << l) - 1 + (lane >> (6 - l))]);
            float pv  = P[(1 << l) - 1 + (lane >> (6 - l))];
            int  bit  = (lane >> (5 - l)) & 1;
            pref *= bit ? pv : (1.f - pv);
        }
        __builtin_nontemporal_store(pref, &nr[63 + lane]);
        float p6 = P[63 + lane];
        float pl = pref * (1.f - p6);
        float pr = pref * p6;
        __builtin_nontemporal_store(pl, &nr[127 + 2 * lane]);
        __builtin_nontemporal_store(pr, &nr[128 + 2 * lane]);
        float p7a = P[127 + 2 * lane];
        float p7b = P[128 + 2 * lane];
        float4v pp;
        pp[0] = pl * (1.f - p7a);
        pp[1] = pl * p7a;
        pp[2] = pr * (1.f - p7b);
        pp[3] = pr * p7b;
        __builtin_nontemporal_store(pp, (float4v*)(pp_out + (size_t)b * NLEAF + 4 * lane));
        float hs = pp[0] * lf.x + pp[1] * lf.y + pp[2] * lf.z + pp[3] * lf.w;
#pragma unroll
        for (int off = 1; off < 64; off <<= 1) hs += __shfl_xor(hs, off, 64);
        if (lane == 0) h_out[b] = hs;
    }
}

extern "C" void kernel_launch(void* const* d_in, const int* in_sizes, int n_in,
                              void* d_out, int out_size, void* d_ws, size_t ws_size,
                              hipStream_t stream) {
    const float* x    = (const float*)d_in[0];
    const float* W1   = (const float*)d_in[1];
    const float* b1   = (const float*)d_in[2];
    const float* W2   = (const float*)d_in[3];
    const float* b2   = (const float*)d_in[4];
    const float* leaf = (const float*)d_in[5];

    float* out    = (float*)d_out;
    float* h_out  = out;                                   // [16384]
    float* pp_out = out + BATCH;                           // [16384*256]
    float* p_out  = pp_out + (size_t)BATCH * NLEAF;        // [16384*255]
    float* nr_out = p_out + (size_t)BATCH * NNODE;         // [16384*255]

    // workspace: 4 MB xp + ~1 MB w1p + 8 KB w2h (p_ws intermediate eliminated)
    half8*    xp   = (half8*)d_ws;
    half8*    w1p  = xp + (size_t)1024 * 4 * 64;
    _Float16* w2h  = (_Float16*)(w1p + (size_t)NNODE * 256);

    hipLaunchKernelGGL(k_pack,  dim3(1024 + NNODE), dim3(256), 0, stream, x, W1, W2, xp, w1p, w2h);
    hipLaunchKernelGGL(k_fused, dim3(256),          dim3(256), 0, stream,
                       xp, w1p, b1, w2h, b2, leaf, h_out, pp_out, p_out, nr_out);
}

// Round 3
// 115.357 us; speedup vs baseline: 1.2116x; 1.2116x over previous
//
#include <hip/hip_runtime.h>

// Problem constants (fixed by the reference).
#define BATCH 16384
#define DIN   128
#define HIDN  16
#define NNODE 255
#define NLEAF 256

typedef _Float16 half8 __attribute__((ext_vector_type(8)));
typedef _Float16 half4 __attribute__((ext_vector_type(4)));
typedef float   float4v __attribute__((ext_vector_type(4)));

// ---------------- combined pack kernel ----------------
// blocks 0..1023: pack x -> f16 B-operand fragments
//   lane L holds B[k=(L>>4)*8+j][n=L&15] (n=batch, k=din); ws: [bt][kc][lane] half8
// blocks 1024..1278: pack W1[n] -> f16 A-operand fragments (LDS-staged)
//   lane L holds A[m=L&15][k=(L>>4)*8+j] (m=hidden, k=din); plus W2[n] -> f16
__global__ __launch_bounds__(256) void k_pack(const float* __restrict__ x, const float* __restrict__ w1,
                                              const float* __restrict__ w2,
                                              half8* __restrict__ xp, half8* __restrict__ w1p,
                                              _Float16* __restrict__ w2h) {
    __shared__ float w[DIN * 17];
    int t = threadIdx.x;
    if (blockIdx.x < 1024) {
        int gid  = blockIdx.x * 256 + t;
        int lane = gid & 63;
        int kc   = (gid >> 6) & 3;
        int bt   = gid >> 8;
        const float4* src = (const float4*)(x + (size_t)(bt * 16 + (lane & 15)) * DIN + kc * 32 + ((lane >> 4) * 8));
        float4 v0 = src[0], v1 = src[1];
        half8 v;
        v[0] = (_Float16)v0.x; v[1] = (_Float16)v0.y; v[2] = (_Float16)v0.z; v[3] = (_Float16)v0.w;
        v[4] = (_Float16)v1.x; v[5] = (_Float16)v1.y; v[6] = (_Float16)v1.z; v[7] = (_Float16)v1.w;
        xp[gid] = v;
    } else {
        int n = blockIdx.x - 1024;
        const float4* src = (const float4*)(w1 + (size_t)n * (DIN * HIDN)) + t * 2;
        float4 a0 = src[0], a1 = src[1];
        int base = t * 8;
#pragma unroll
        for (int e = 0; e < 4; ++e) {
            int idx0 = base + e, idx1 = base + 4 + e;
            w[(idx0 >> 4) * 17 + (idx0 & 15)] = (&a0.x)[e];
            w[(idx1 >> 4) * 17 + (idx1 & 15)] = (&a1.x)[e];
        }
        __syncthreads();
        int L  = t & 63;
        int kc = t >> 6;
        int m  = L & 15;
        int k0 = kc * 32 + (L >> 4) * 8;
        half8 v;
#pragma unroll
        for (int j = 0; j < 8; ++j) v[j] = (_Float16)w[(k0 + j) * 17 + m];
        w1p[(size_t)n * 256 + t] = v;
        if (t < HIDN) w2h[n * HIDN + t] = (_Float16)w2[n * HIDN + t];
    }
}

// ---------------- fused MLP + tree kernel, 32 rows / block ----------------
// Grid 512 blocks (2/CU via 33.3 KB LDS), 256 threads (4 waves).
// Phase 1 (MLP): waves split the 255 nodes round-robin (n == wv mod 4); each wave
//   computes BOTH 16-row tiles for its nodes via double MFMA, writing
//   sigmoid(logit) into LDS sp[32][260]. bq is only [2][4] = 32 VGPRs so the
//   whole operand set stays register-resident (round-2's 88-VGPR count showed the
//   64-VGPR bq was NOT being kept in registers). Depth-1 operand prefetch.
// Phase 2 (tree): one barrier, each wave scans 8 rows from LDS. Plain stores
//   (NT stores were bundled into the round-1 regression; reverted).
__global__ __launch_bounds__(256, 2) void k_fused(const half8* __restrict__ xp, const half8* __restrict__ w1p,
                                                  const float* __restrict__ b1, const _Float16* __restrict__ w2h,
                                                  const float* __restrict__ b2, const float* __restrict__ leaf,
                                                  float* __restrict__ h_out, float* __restrict__ pp_out,
                                                  float* __restrict__ p_out, float* __restrict__ nr_out) {
    __shared__ float sp[32][260];                 // stride 260 words -> conflict-free enough
    int wv   = threadIdx.x >> 6;
    int lane = threadIdx.x & 63;
    int q    = lane >> 4;
    int bt0  = blockIdx.x * 2;                    // two 16-row tiles

    // B-fragments for both tiles (identical in every wave): 8 half8 = 32 VGPRs
    half8 bq[2][4];
#pragma unroll
    for (int t = 0; t < 2; ++t)
#pragma unroll
        for (int kc = 0; kc < 4; ++kc)
            bq[t][kc] = xp[(size_t)((bt0 + t) * 4 + kc) * 64 + lane];
    asm volatile("" ::: "memory");

    // ---- phase 1: MLP over this wave's nodes ----
    int cnt = (wv < 3) ? 64 : 63;                 // 255 = 64+64+64+63
    int n   = wv;
    half8 a[4];
#pragma unroll
    for (int kc = 0; kc < 4; ++kc) a[kc] = w1p[(size_t)(n * 4 + kc) * 64 + lane];
    float4 b1f = ((const float4*)(b1 + n * HIDN))[q];
    half4  a2  = *(const half4*)(w2h + n * HIDN + q * 4);
    float  b2v = b2[n];

    for (int i = 0; i < cnt; ++i) {
        int nn = n + ((i + 1 < cnt) ? 4 : 0);     // branch-free clamp
        half8 an[4];
#pragma unroll
        for (int kc = 0; kc < 4; ++kc) an[kc] = w1p[(size_t)(nn * 4 + kc) * 64 + lane];
        float4 b1n = ((const float4*)(b1 + nn * HIDN))[q];
        half4  a2n = *(const half4*)(w2h + nn * HIDN + q * 4);
        float  b2n = b2[nn];

#pragma unroll
        for (int t = 0; t < 2; ++t) {
            float4v acc = {b1f.x, b1f.y, b1f.z, b1f.w};
#pragma unroll
            for (int kc = 0; kc < 4; ++kc)
                acc = __builtin_amdgcn_mfma_f32_16x16x32_f16(a[kc], bq[t][kc], acc, 0, 0, 0);
            half4 rb;
#pragma unroll
            for (int r = 0; r < 4; ++r) rb[r] = (_Float16)fmaxf(acc[r], 0.f);
            float4v acc2 = {b2v, b2v, b2v, b2v};
            acc2 = __builtin_amdgcn_mfma_f32_16x16x16f16(a2, rb, acc2, 0, 0, 0);
            if (lane < 16)
                sp[t * 16 + lane][n] =
                    __builtin_amdgcn_rcpf(1.f + __builtin_amdgcn_exp2f(-1.44269504088896f * acc2[0]));
        }
#pragma unroll
        for (int kc = 0; kc < 4; ++kc) a[kc] = an[kc];
        b1f = b1n; a2 = a2n; b2v = b2n;
        n = nn;
    }
    __syncthreads();

    // ---- phase 2: tree scan, 8 rows per wave, straight from LDS ----
    const float4 lf = *(const float4*)(leaf + 4 * lane);
    for (int rr = 0; rr < 8; ++rr) {
        int r = wv * 8 + rr;
        int b = blockIdx.x * 32 + r;
        const float* P = &sp[r][0];
        float* nr = nr_out + (size_t)b * NNODE;

        // p_out copy, coalesced
#pragma unroll
        for (int c = 0; c < 4; ++c) {
            int idx = c * 64 + lane;
            if (idx < NNODE)
                p_out[(size_t)b * NNODE + idx] = P[idx];
        }

        float pref = 1.f;
#pragma unroll
        for (int l = 0; l < 6; ++l) {
            if ((lane & ((1 << (6 - l)) - 1)) == 0)
                nr[(1 << l) - 1 + (lane >> (6 - l))] = pref;
            float pv  = P[(1 << l) - 1 + (lane >> (6 - l))];
            int  bit  = (lane >> (5 - l)) & 1;
            pref *= bit ? pv : (1.f - pv);
        }
        nr[63 + lane] = pref;
        float p6 = P[63 + lane];
        float pl = pref * (1.f - p6);
        float pr = pref * p6;
        nr[127 + 2 * lane] = pl;
        nr[128 + 2 * lane] = pr;
        float p7a = P[127 + 2 * lane];
        float p7b = P[128 + 2 * lane];
        float4v pp;
        pp[0] = pl * (1.f - p7a);
        pp[1] = pl * p7a;
        pp[2] = pr * (1.f - p7b);
        pp[3] = pr * p7b;
        *(float4v*)(pp_out + (size_t)b * NLEAF + 4 * lane) = pp;
        float hs = pp[0] * lf.x + pp[1] * lf.y + pp[2] * lf.z + pp[3] * lf.w;
#pragma unroll
        for (int off = 1; off < 64; off <<= 1) hs += __shfl_xor(hs, off, 64);
        if (lane == 0) h_out[b] = hs;
    }
}

extern "C" void kernel_launch(void* const* d_in, const int* in_sizes, int n_in,
                              void* d_out, int out_size, void* d_ws, size_t ws_size,
                              hipStream_t stream) {
    const float* x    = (const float*)d_in[0];
    const float* W1   = (const float*)d_in[1];
    const float* b1   = (const float*)d_in[2];
    const float* W2   = (const float*)d_in[3];
    const float* b2   = (const float*)d_in[4];
    const float* leaf = (const float*)d_in[5];

    float* out    = (float*)d_out;
    float* h_out  = out;                                   // [16384]
    float* pp_out = out + BATCH;                           // [16384*256]
    float* p_out  = pp_out + (size_t)BATCH * NLEAF;        // [16384*255]
    float* nr_out = p_out + (size_t)BATCH * NNODE;         // [16384*255]

    // workspace: 4 MB xp + ~1 MB w1p + 8 KB w2h (p_ws intermediate eliminated)
    half8*    xp   = (half8*)d_ws;
    half8*    w1p  = xp + (size_t)1024 * 4 * 64;
    _Float16* w2h  = (_Float16*)(w1p + (size_t)NNODE * 256);

    hipLaunchKernelGGL(k_pack,  dim3(1024 + NNODE), dim3(256), 0, stream, x, W1, W2, xp, w1p, w2h);
    hipLaunchKernelGGL(k_fused, dim3(512),          dim3(256), 0, stream,
                       xp, w1p, b1, w2h, b2, leaf, h_out, pp_out, p_out, nr_out);
}